// Round 11
// baseline (239.655 us; speedup 1.0000x reference)
//
#include <hip/hip_runtime.h>

// Wav2Vec2BertSelfAttention on MI355X (gfx950)
// B=4, S=1024, HID=1024, NH=16, HD=64, LEFT=64, RIGHT=8, NUM_POS=73
//
// Round 11: exact round-8 pipeline (best: 176us), gemm epilogue reverted to
// scattered scalar stores (r10's LDS-staged epilogue regressed). One change
// in attn: __launch_bounds__(256,3) (VGPR cap 170, est. use ~145) -> 3
// blocks/CU = 12 waves/CU (+50% TLP), plus nontemporal probs stores
// (write-once 268MB stream; keep K/V L2-resident).
//   Q''[qt][dcg][lq][dc2][8]   K''[kt][half][dcg][p][dc2][8]
//   V''[vt2][db][lq][Qr][8]   (per (b,head) 128KB blocks, dense 1KB loads)

using short8 = __attribute__((ext_vector_type(8))) short;
using f32x4  = __attribute__((ext_vector_type(4))) float;
using fl4    = __attribute__((ext_vector_type(4))) float;
using u16x4  = __attribute__((ext_vector_type(4))) unsigned short;

#define MFMA16(a, b, c) __builtin_amdgcn_mfma_f32_16x16x32_bf16((a), (b), (c), 0, 0, 0)

// 0.125 (1/sqrt(64)) * log2(e)
#define SCL2E 0.18033688011112042f

__device__ __forceinline__ float bf2f(unsigned short u) {
  union { unsigned int i; float f; } c;
  c.i = ((unsigned int)u) << 16;
  return c.f;
}
__device__ __forceinline__ unsigned short f2bf(float f) {
  union { float f; unsigned int i; } c;
  c.f = f;
  unsigned int x = c.i;
  return (unsigned short)((x + 0x7fffu + ((x >> 16) & 1u)) >> 16);  // RNE
}
__device__ __forceinline__ float u2f(unsigned u) {
  union { unsigned i; float f; } c;
  c.i = u;
  return c.f;
}

__device__ __forceinline__ void gload_lds16(const void* g, void* l) {
  __builtin_amdgcn_global_load_lds(
      (const __attribute__((address_space(1))) void*)g,
      (__attribute__((address_space(3))) void*)l, 16, 0, 0);
}

// ---------------------------------------------------------------- convert
__global__ void cvt_f32_bf16(const float* __restrict__ in,
                             unsigned short* __restrict__ out, int n4) {
  int i = blockIdx.x * blockDim.x + threadIdx.x;
  int stride = gridDim.x * blockDim.x;
  for (; i < n4; i += stride) {
    fl4 v = ((const fl4*)in)[i];
    u16x4 o;
    o[0] = f2bf(v[0]); o[1] = f2bf(v[1]); o[2] = f2bf(v[2]); o[3] = f2bf(v[3]);
    ((u16x4*)out)[i] = o;
  }
}

__global__ void cvt_w4(const float* __restrict__ w0, const float* __restrict__ w1,
                       const float* __restrict__ w2, const float* __restrict__ w3,
                       unsigned short* __restrict__ o0, unsigned short* __restrict__ o1,
                       unsigned short* __restrict__ o2, unsigned short* __restrict__ o3) {
  const int which = blockIdx.x >> 8;
  const float* in = which == 0 ? w0 : which == 1 ? w1 : which == 2 ? w2 : w3;
  unsigned short* out = which == 0 ? o0 : which == 1 ? o1 : which == 2 ? o2 : o3;
  int i = (blockIdx.x & 255) * 256 + threadIdx.x;
#pragma unroll
  for (int it = 0; it < 4; ++it, i += 65536) {
    fl4 v = ((const fl4*)in)[i];
    u16x4 o;
    o[0] = f2bf(v[0]); o[1] = f2bf(v[1]); o[2] = f2bf(v[2]); o[3] = f2bf(v[3]);
    ((u16x4*)out)[i] = o;
  }
}

__global__ void cvt_demb(const float* __restrict__ in,
                         unsigned short* __restrict__ out) {
  int i = blockIdx.x * blockDim.x + threadIdx.x;
  if (i < 80 * 64) out[i] = (i < 73 * 64) ? f2bf(in[i]) : (unsigned short)0;
}

// ---------------------------------------------------------------- fused QKV GEMM
// r=0 Q = X@Wq^T (+bq), r=1 K = X@Wk^T (+bk), r=2 V = Wv@X^T (+bv, row)
// outputs written in attn-fragment-tiled per-(b,head) layouts (r8 epilogue).
__global__ __launch_bounds__(256)
void gemm_qkv3(const unsigned short* __restrict__ X,
               const unsigned short* __restrict__ Bq,
               const unsigned short* __restrict__ Bk,
               const unsigned short* __restrict__ Bv,
               const float* __restrict__ biq, const float* __restrict__ bik,
               const float* __restrict__ biv,
               unsigned short* __restrict__ Cq, unsigned short* __restrict__ Ck,
               unsigned short* __restrict__ Cv) {
  __shared__ unsigned short lA[128 * 32];
  __shared__ unsigned short lB[128 * 32];
  const int i = blockIdx.x;
  const int wgid = (i & 7) * 96 + (i >> 3);   // XCD-chunked (768 % 8 == 0)
  const int r = wgid >> 8;
  const int id = wgid & 255;
  int bm, bn;
  const unsigned short *Aa, *Bb;
  if (r == 2) {           // V: A=Wv rows (o=dglob), B=X rows (s-global)
    bm = (id >> 5) * 128; bn = (id & 31) * 128;
    Aa = Bv; Bb = X;
  } else {                // Q/K: A=X rows (s-global), B=W rows (dglob)
    bm = (id >> 3) * 128; bn = (id & 7) * 128;
    Aa = X; Bb = (r == 0) ? Bq : Bk;
  }
  const float* bias = (r == 0) ? biq : (r == 1) ? bik : biv;

  const int tid = threadIdx.x;
  const int wave = tid >> 6, lane = tid & 63;
  const int wm = wave >> 1, wn = wave & 1;

  f32x4 acc[4][4];
#pragma unroll
  for (int m = 0; m < 4; ++m)
#pragma unroll
    for (int n = 0; n < 4; ++n) acc[m][n] = (f32x4){0.f, 0.f, 0.f, 0.f};

  const int t0 = tid, t1 = tid + 256;
  const int ar0 = t0 >> 2, ak0 = (t0 & 3) * 8;
  const int ar1 = t1 >> 2, ak1 = (t1 & 3) * 8;
  const unsigned short* Ab = Aa + (size_t)bm * 1024;
  const unsigned short* Bbb = Bb + (size_t)bn * 1024;
  const int fr = lane & 15, fk = (lane >> 4) * 8;

  for (int kt = 0; kt < 1024; kt += 32) {
    gload_lds16(Ab + (size_t)ar0 * 1024 + kt + ak0, (void*)&lA[(wave * 64) * 8]);
    gload_lds16(Ab + (size_t)ar1 * 1024 + kt + ak1, (void*)&lA[2048 + (wave * 64) * 8]);
    gload_lds16(Bbb + (size_t)ar0 * 1024 + kt + ak0, (void*)&lB[(wave * 64) * 8]);
    gload_lds16(Bbb + (size_t)ar1 * 1024 + kt + ak1, (void*)&lB[2048 + (wave * 64) * 8]);
    __syncthreads();
    short8 af[4], bf[4];
#pragma unroll
    for (int m = 0; m < 4; ++m)
      af[m] = *(const short8*)&lA[(wm * 64 + m * 16 + fr) * 32 + fk];
#pragma unroll
    for (int n = 0; n < 4; ++n)
      bf[n] = *(const short8*)&lB[(wn * 64 + n * 16 + fr) * 32 + fk];
#pragma unroll
    for (int m = 0; m < 4; ++m)
#pragma unroll
      for (int n = 0; n < 4; ++n) acc[m][n] = MFMA16(af[m], bf[n], acc[m][n]);
    __syncthreads();
  }

  const int cr = (lane >> 4) * 4, cc = lane & 15;
#pragma unroll
  for (int m = 0; m < 4; ++m)
#pragma unroll
    for (int n = 0; n < 4; ++n) {
      const int col = bn + wn * 64 + n * 16 + cc;
#pragma unroll
      for (int g = 0; g < 4; ++g) {
        const int row = bm + wm * 64 + m * 16 + cr + g;
        if (r == 2) {
          // V: row = dglob, col = s-global
          const float v = acc[m][n][g] + bias[row];
          const int head = row >> 6, d = row & 63;
          const int b2 = col >> 10, sl = col & 1023, kk = sl & 31;
          size_t idx = ((size_t)((b2 << 4) + head) << 16) +
                       (size_t)(((sl >> 5) * 4 + (d >> 4)) * 512) +
                       (d & 15) * 32 + ((kk >> 3) * 8) + (kk & 7);
          Cv[idx] = f2bf(v);
        } else {
          // Q/K: row = s-global, col = dglob
          const float v = acc[m][n][g] + bias[col];
          const int head = col >> 6, d = col & 63;
          const int b2 = row >> 10, sl = row & 1023;
          const int dc = d >> 3;
          const size_t hb = (size_t)((b2 << 4) + head) << 16;
          if (r == 0) {
            size_t idx = hb +
                         (size_t)((((sl >> 4) * 2 + (dc >> 2)) * 16 + (sl & 15)) * 32) +
                         (dc & 3) * 8 + (d & 7);
            Cq[idx] = f2bf(v);
          } else {
            const int kt2 = sl >> 5;
            const int p = ((sl >> 3) & 3) * 4 + (sl & 3);
            const int half = (sl >> 2) & 1;
            size_t idx = hb +
                         (size_t)((((kt2 * 2 + half) * 2 + (dc >> 2)) * 512)) +
                         p * 32 + (dc & 3) * 8 + (d & 7);
            Ck[idx] = f2bf(v);
          }
        }
      }
    }
}

// ---------------------------------------------------------------- GEMM f32 out
__global__ __launch_bounds__(256)
void gemm_nt_f32(const unsigned short* __restrict__ A,
                 const unsigned short* __restrict__ B,
                 const float* __restrict__ bias, float* __restrict__ Cp) {
  __shared__ unsigned short lA[128 * 32];
  __shared__ unsigned short lB[128 * 32];
  const int tid = threadIdx.x;
  const int wave = tid >> 6, lane = tid & 63;
  const int wm = wave >> 1, wn = wave & 1;
  const int bm = blockIdx.x * 128, bn = blockIdx.y * 128;

  f32x4 acc[4][4];
#pragma unroll
  for (int m = 0; m < 4; ++m)
#pragma unroll
    for (int n = 0; n < 4; ++n) acc[m][n] = (f32x4){0.f, 0.f, 0.f, 0.f};

  const int t0 = tid, t1 = tid + 256;
  const int ar0 = t0 >> 2, ak0 = (t0 & 3) * 8;
  const int ar1 = t1 >> 2, ak1 = (t1 & 3) * 8;
  const unsigned short* Ab = A + (size_t)bm * 1024;
  const unsigned short* Bb = B + (size_t)bn * 1024;
  const int fr = lane & 15, fk = (lane >> 4) * 8;

  for (int kt = 0; kt < 1024; kt += 32) {
    gload_lds16(Ab + (size_t)ar0 * 1024 + kt + ak0, (void*)&lA[(wave * 64) * 8]);
    gload_lds16(Ab + (size_t)ar1 * 1024 + kt + ak1, (void*)&lA[2048 + (wave * 64) * 8]);
    gload_lds16(Bb + (size_t)ar0 * 1024 + kt + ak0, (void*)&lB[(wave * 64) * 8]);
    gload_lds16(Bb + (size_t)ar1 * 1024 + kt + ak1, (void*)&lB[2048 + (wave * 64) * 8]);
    __syncthreads();
    short8 af[4], bf[4];
#pragma unroll
    for (int m = 0; m < 4; ++m)
      af[m] = *(const short8*)&lA[(wm * 64 + m * 16 + fr) * 32 + fk];
#pragma unroll
    for (int n = 0; n < 4; ++n)
      bf[n] = *(const short8*)&lB[(wn * 64 + n * 16 + fr) * 32 + fk];
#pragma unroll
    for (int m = 0; m < 4; ++m)
#pragma unroll
      for (int n = 0; n < 4; ++n) acc[m][n] = MFMA16(af[m], bf[n], acc[m][n]);
    __syncthreads();
  }

  const int cr = (lane >> 4) * 4, cc = lane & 15;
#pragma unroll
  for (int m = 0; m < 4; ++m)
#pragma unroll
    for (int n = 0; n < 4; ++n) {
      const int col = bn + wn * 64 + n * 16 + cc;
#pragma unroll
      for (int g = 0; g < 4; ++g) {
        const int row = bm + wm * 64 + m * 16 + cr + g;
        Cp[(size_t)row * 1024 + col] = acc[m][n][g] + bias[col];
      }
    }
}

// ---------------------------------------------------------------- attention
// Block = (b,h, 32 q-rows = groups A,B of 16). 4 waves split k (256 cols).
// All Q/K/V loads are dense 1KB wave loads from the tiled layouts.
// r8 structure; launch_bounds (256,3) for 3 blocks/CU; nt probs stores.
__global__ __launch_bounds__(256, 3)
void attn_kernel(const unsigned short* __restrict__ q,
                 const unsigned short* __restrict__ k,
                 const unsigned short* __restrict__ vt,
                 const unsigned short* __restrict__ demb_bf,
                 float* __restrict__ probs,
                 unsigned short* __restrict__ ctx) {
  const int i = blockIdx.x;
  const int x = i & 7, s = i >> 3;            // 2048 blocks, 2048%8==0
  const int bh = ((s >> 5) << 3) + x;         // 32 same-XCD blocks share bh
  const int qseg = s & 31;
  const int hd = bh & 15, b = bh >> 4;
  const int tid = threadIdx.x, w = tid >> 6, lane = tid & 63;
  const int lq = lane & 15, Qr = lane >> 4;
  const int qA = qseg * 32, qB = qA + 16;

  __shared__ unsigned short qdc[32][78];   // bf16, PRE-SCALED by SCL2E
  __shared__ float reds[4][32];
  __shared__ float red[4][4][32][16];      // 32 KB partial PV

  const size_t hb = (size_t)((b << 4) + hd) << 16;  // per-(b,head) 64K u16 block
  const int lo16 = lq * 32 + Qr * 8;                // lane offset in 512-u16 block

  // Q frags (dense): Q''[qt][dcg][lq][dc2][8]
  const unsigned short* qh = q + hb + (size_t)(qseg * 4) * 512;
  short8 bqA0 = *(const short8*)(qh + lo16);
  short8 bqA1 = *(const short8*)(qh + 512 + lo16);
  short8 bqB0 = *(const short8*)(qh + 1024 + lo16);
  short8 bqB1 = *(const short8*)(qh + 1536 + lo16);

  // qd[q][p] = (Q[q] . dist_emb[p]) * SCL2E
  for (int pgq = w; pgq < 10; pgq += 4) {
    const int qblk = pgq >= 5;
    const int pg = qblk ? pgq - 5 : pgq;
    const unsigned short* dp = demb_bf + (size_t)(pg * 16 + lq) * 64 + Qr * 8;
    short8 a0 = *(const short8*)dp;
    short8 a1 = *(const short8*)(dp + 32);
    f32x4 c = (f32x4){0.f, 0.f, 0.f, 0.f};
    c = MFMA16(a0, qblk ? bqB0 : bqA0, c);
    c = MFMA16(a1, qblk ? bqB1 : bqA1, c);
#pragma unroll
    for (int g = 0; g < 4; ++g) {
      const int p = pg * 16 + Qr * 4 + g;
      if (p < 73) qdc[qblk * 16 + lq][p] = f2bf(c[g] * SCL2E);
    }
  }
  __syncthreads();

  const float qd0A = bf2f(qdc[lq][0]),       qd72A = bf2f(qdc[lq][72]);
  const float qd0B = bf2f(qdc[16 + lq][0]),  qd72B = bf2f(qdc[16 + lq][72]);

  float ssumA = 0.f, ssumB = 0.f;
  unsigned pafA[8][4], pafB[8][4];
  f32x4 oA0 = (f32x4){0.f, 0.f, 0.f, 0.f}, oA1 = oA0, oA2 = oA0, oA3 = oA0;
  f32x4 oB0 = oA0, oB1 = oA0, oB2 = oA0, oB3 = oA0;

  // K''[kt][half][dcg]: tile base = kt*2048; V''[vt2][db]: tile base = vt2*2048
  const unsigned short* kh = k + hb + (size_t)(w * 8) * 2048 + lo16;
  const unsigned short* vh = vt + hb + (size_t)(w * 8) * 2048 + lo16;

#pragma unroll
  for (int t = 0; t < 8; ++t) {
    const unsigned short* kp = kh + t * 2048;
    short8 ae0 = *(const short8*)kp;
    short8 ae1 = *(const short8*)(kp + 512);
    short8 ao0 = *(const short8*)(kp + 1024);
    short8 ao1 = *(const short8*)(kp + 1536);
    const unsigned short* vp = vh + t * 2048;
    short8 v0 = *(const short8*)vp;
    short8 v1 = *(const short8*)(vp + 512);
    short8 v2 = *(const short8*)(vp + 1024);
    short8 v3 = *(const short8*)(vp + 1536);

    f32x4 seA = (f32x4){0.f, 0.f, 0.f, 0.f}, soA = seA, seB = seA, soB = seA;
    seA = MFMA16(ae0, bqA0, seA); seA = MFMA16(ae1, bqA1, seA);
    soA = MFMA16(ao0, bqA0, soA); soA = MFMA16(ao1, bqA1, soA);
    seB = MFMA16(ae0, bqB0, seB); seB = MFMA16(ae1, bqB1, seB);
    soB = MFMA16(ao0, bqB0, soB); soB = MFMA16(ao1, bqB1, soB);

    const int tglob = w * 8 + t;
    // ---- group A
    {
      float pe[4], po[4];
      if (tglob * 32 + 31 < qA - 64) {
#pragma unroll
        for (int g = 0; g < 4; ++g) {
          pe[g] = exp2f(fmaf(seA[g], SCL2E, qd0A));
          po[g] = exp2f(fmaf(soA[g], SCL2E, qd0A));
        }
      } else if (tglob * 32 > qA + 23) {
#pragma unroll
        for (int g = 0; g < 4; ++g) {
          pe[g] = exp2f(fmaf(seA[g], SCL2E, qd72A));
          po[g] = exp2f(fmaf(soA[g], SCL2E, qd72A));
        }
      } else {
        const int c0 = tglob * 32 + Qr * 8 - (qA + lq);
#pragma unroll
        for (int g = 0; g < 4; ++g) {
          int d0 = c0 + g;     d0 = d0 < -64 ? -64 : (d0 > 8 ? 8 : d0);
          int d1 = c0 + 4 + g; d1 = d1 < -64 ? -64 : (d1 > 8 ? 8 : d1);
          pe[g] = exp2f(fmaf(seA[g], SCL2E, bf2f(qdc[lq][d0 + 64])));
          po[g] = exp2f(fmaf(soA[g], SCL2E, bf2f(qdc[lq][d1 + 64])));
        }
      }
#pragma unroll
      for (int g = 0; g < 4; ++g) ssumA += pe[g] + po[g];
      asm("v_cvt_pk_bf16_f32 %0, %1, %2" : "=v"(pafA[t][0]) : "v"(pe[0]), "v"(pe[1]));
      asm("v_cvt_pk_bf16_f32 %0, %1, %2" : "=v"(pafA[t][1]) : "v"(pe[2]), "v"(pe[3]));
      asm("v_cvt_pk_bf16_f32 %0, %1, %2" : "=v"(pafA[t][2]) : "v"(po[0]), "v"(po[1]));
      asm("v_cvt_pk_bf16_f32 %0, %1, %2" : "=v"(pafA[t][3]) : "v"(po[2]), "v"(po[3]));
      union { unsigned u[4]; short8 s8v; } uu;
      uu.u[0] = pafA[t][0]; uu.u[1] = pafA[t][1];
      uu.u[2] = pafA[t][2]; uu.u[3] = pafA[t][3];
      const short8 pa = uu.s8v;
      oA0 = MFMA16(pa, v0, oA0);
      oA1 = MFMA16(pa, v1, oA1);
      oA2 = MFMA16(pa, v2, oA2);
      oA3 = MFMA16(pa, v3, oA3);
    }
    // ---- group B
    {
      float pe[4], po[4];
      if (tglob * 32 + 31 < qB - 64) {
#pragma unroll
        for (int g = 0; g < 4; ++g) {
          pe[g] = exp2f(fmaf(seB[g], SCL2E, qd0B));
          po[g] = exp2f(fmaf(soB[g], SCL2E, qd0B));
        }
      } else if (tglob * 32 > qB + 23) {
#pragma unroll
        for (int g = 0; g < 4; ++g) {
          pe[g] = exp2f(fmaf(seB[g], SCL2E, qd72B));
          po[g] = exp2f(fmaf(soB[g], SCL2E, qd72B));
        }
      } else {
        const int c0 = tglob * 32 + Qr * 8 - (qB + lq);
#pragma unroll
        for (int g = 0; g < 4; ++g) {
          int d0 = c0 + g;     d0 = d0 < -64 ? -64 : (d0 > 8 ? 8 : d0);
          int d1 = c0 + 4 + g; d1 = d1 < -64 ? -64 : (d1 > 8 ? 8 : d1);
          pe[g] = exp2f(fmaf(seB[g], SCL2E, bf2f(qdc[16 + lq][d0 + 64])));
          po[g] = exp2f(fmaf(soB[g], SCL2E, bf2f(qdc[16 + lq][d1 + 64])));
        }
      }
#pragma unroll
      for (int g = 0; g < 4; ++g) ssumB += pe[g] + po[g];
      asm("v_cvt_pk_bf16_f32 %0, %1, %2" : "=v"(pafB[t][0]) : "v"(pe[0]), "v"(pe[1]));
      asm("v_cvt_pk_bf16_f32 %0, %1, %2" : "=v"(pafB[t][1]) : "v"(pe[2]), "v"(pe[3]));
      asm("v_cvt_pk_bf16_f32 %0, %1, %2" : "=v"(pafB[t][2]) : "v"(po[0]), "v"(po[1]));
      asm("v_cvt_pk_bf16_f32 %0, %1, %2" : "=v"(pafB[t][3]) : "v"(po[2]), "v"(po[3]));
      union { unsigned u[4]; short8 s8v; } uu;
      uu.u[0] = pafB[t][0]; uu.u[1] = pafB[t][1];
      uu.u[2] = pafB[t][2]; uu.u[3] = pafB[t][3];
      const short8 pa = uu.s8v;
      oB0 = MFMA16(pa, v0, oB0);
      oB1 = MFMA16(pa, v1, oB1);
      oB2 = MFMA16(pa, v2, oB2);
      oB3 = MFMA16(pa, v3, oB3);
    }
  }
  ssumA += __shfl_xor(ssumA, 16, 64);
  ssumA += __shfl_xor(ssumA, 32, 64);
  ssumB += __shfl_xor(ssumB, 16, 64);
  ssumB += __shfl_xor(ssumB, 32, 64);
  if (lane < 16) {
    reds[w][lane] = ssumA;
    reds[w][16 + lane] = ssumB;
  }
#pragma unroll
  for (int g = 0; g < 4; ++g) {
    red[w][0][Qr * 4 + g][lq] = oA0[g];
    red[w][1][Qr * 4 + g][lq] = oA1[g];
    red[w][2][Qr * 4 + g][lq] = oA2[g];
    red[w][3][Qr * 4 + g][lq] = oA3[g];
    red[w][0][16 + Qr * 4 + g][lq] = oB0[g];
    red[w][1][16 + Qr * 4 + g][lq] = oB1[g];
    red[w][2][16 + Qr * 4 + g][lq] = oB2[g];
    red[w][3][16 + Qr * 4 + g][lq] = oB3[g];
  }
  __syncthreads();

  const float invA =
      1.0f / (reds[0][lq] + reds[1][lq] + reds[2][lq] + reds[3][lq]);
  const float invB = 1.0f / (reds[0][16 + lq] + reds[1][16 + lq] +
                             reds[2][16 + lq] + reds[3][16 + lq]);
  float* prowA = probs + ((size_t)bh * 1024 + qA + lq) * 1024 + w * 256 + Qr * 8;
  float* prowB = prowA + (size_t)16 * 1024;
#pragma unroll
  for (int t = 0; t < 8; ++t) {
    f32x4 p0, p1;
    p0[0] = u2f(pafA[t][0] << 16) * invA;
    p0[1] = u2f(pafA[t][0] & 0xffff0000u) * invA;
    p0[2] = u2f(pafA[t][1] << 16) * invA;
    p0[3] = u2f(pafA[t][1] & 0xffff0000u) * invA;
    p1[0] = u2f(pafA[t][2] << 16) * invA;
    p1[1] = u2f(pafA[t][2] & 0xffff0000u) * invA;
    p1[2] = u2f(pafA[t][3] << 16) * invA;
    p1[3] = u2f(pafA[t][3] & 0xffff0000u) * invA;
    __builtin_nontemporal_store(p0, (f32x4*)&prowA[t * 32]);
    __builtin_nontemporal_store(p1, (f32x4*)&prowA[t * 32 + 4]);
    f32x4 q0, q1;
    q0[0] = u2f(pafB[t][0] << 16) * invB;
    q0[1] = u2f(pafB[t][0] & 0xffff0000u) * invB;
    q0[2] = u2f(pafB[t][1] << 16) * invB;
    q0[3] = u2f(pafB[t][1] & 0xffff0000u) * invB;
    q1[0] = u2f(pafB[t][2] << 16) * invB;
    q1[1] = u2f(pafB[t][2] & 0xffff0000u) * invB;
    q1[2] = u2f(pafB[t][3] << 16) * invB;
    q1[3] = u2f(pafB[t][3] & 0xffff0000u) * invB;
    __builtin_nontemporal_store(q0, (f32x4*)&prowB[t * 32]);
    __builtin_nontemporal_store(q1, (f32x4*)&prowB[t * 32 + 4]);
  }

  // ctx: thread -> q = tid>>3 (0..31), d = (tid&7)*8 + j
  {
    const int qrow = tid >> 3;
    const int d0 = (tid & 7) * 8;
    const float invq = 1.0f / (reds[0][qrow] + reds[1][qrow] +
                               reds[2][qrow] + reds[3][qrow]);
    u16x4 cv0, cv1;
#pragma unroll
    for (int j = 0; j < 8; ++j) {
      const int d = d0 + j;
      const int db = d >> 4, dd = d & 15;
      float sum = red[0][db][qrow][dd] + red[1][db][qrow][dd] +
                  red[2][db][qrow][dd] + red[3][db][qrow][dd];
      if (j < 4) cv0[j] = f2bf(sum * invq);
      else       cv1[j - 4] = f2bf(sum * invq);
    }
    unsigned short* cb =
        ctx + ((size_t)(b * 1024 + qA + qrow)) * 1024 + hd * 64 + d0;
    *(u16x4*)cb = cv0;
    *(u16x4*)(cb + 4) = cv1;
  }
}

// ---------------------------------------------------------------- launch
extern "C" void kernel_launch(void* const* d_in, const int* in_sizes, int n_in,
                              void* d_out, int out_size, void* d_ws, size_t ws_size,
                              hipStream_t stream) {
  const float* hs = (const float*)d_in[0];
  const float* Wq = (const float*)d_in[1];
  const float* bq = (const float*)d_in[2];
  const float* Wk = (const float*)d_in[3];
  const float* bk = (const float*)d_in[4];
  const float* Wv = (const float*)d_in[5];
  const float* bv = (const float*)d_in[6];
  const float* Wo = (const float*)d_in[7];
  const float* bo = (const float*)d_in[8];
  const float* de = (const float*)d_in[9];

  float* out = (float*)d_out;
  float* probs = out + (size_t)4 * 1024 * 1024;

  char* ws = (char*)d_ws;
  unsigned short* Xb  = (unsigned short*)(ws);                      // -> ctx later
  unsigned short* Wqb = (unsigned short*)(ws + ((size_t)8 << 20));  // -> demb later
  unsigned short* Wkb = (unsigned short*)(ws + ((size_t)10 << 20));
  unsigned short* Wvb = (unsigned short*)(ws + ((size_t)12 << 20));
  unsigned short* Wob = (unsigned short*)(ws + ((size_t)14 << 20));
  unsigned short* Qb  = (unsigned short*)(ws + ((size_t)16 << 20));
  unsigned short* Kb  = (unsigned short*)(ws + ((size_t)24 << 20));
  unsigned short* Vt  = (unsigned short*)(ws + ((size_t)32 << 20));
  unsigned short* Db  = Wqb;  // demb_bf (after QKV gemm)
  unsigned short* Cx  = Xb;   // ctx (after QKV gemm; X dead)

  cvt_f32_bf16<<<dim3(1024), dim3(256), 0, stream>>>(hs, Xb, (4 * 1024 * 1024) / 4);
  cvt_w4<<<dim3(1024), dim3(256), 0, stream>>>(Wq, Wk, Wv, Wo, Wqb, Wkb, Wvb, Wob);

  gemm_qkv3<<<dim3(768), dim3(256), 0, stream>>>(Xb, Wqb, Wkb, Wvb, bq, bk, bv,
                                                 Qb, Kb, Vt);
  cvt_demb<<<dim3(20), dim3(256), 0, stream>>>(de, Db);

  attn_kernel<<<dim3(2048), dim3(256), 0, stream>>>(Qb, Kb, Vt, Db, probs, Cx);

  gemm_nt_f32<<<dim3(32, 8), dim3(256), 0, stream>>>(Cx, Wob, bo, out);
}

// Round 12
// 182.171 us; speedup vs baseline: 1.3155x; 1.3155x over previous
//
#include <hip/hip_runtime.h>

// Wav2Vec2BertSelfAttention on MI355X (gfx950)
// B=4, S=1024, HID=1024, NH=16, HD=64, LEFT=64, RIGHT=8, NUM_POS=73
//
// Round 12: exact round-8 pipeline (best known: 176us). r9/r10/r11 levers all
// reverted (prefetch rotation, LDS epilogue, occupancy hint -> VGPR spill).
// Only mechanical trims: cvt_demb folded into cvt_w4 (Db gets its own ws slot
// at +40MB, no aliasing), XCD swizzle on gemm_nt_f32.
//   Q''[qt][dcg][lq][dc2][8]   K''[kt][half][dcg][p][dc2][8]
//   V''[vt2][db][lq][Qr][8]   (per (b,head) 128KB blocks, dense 1KB loads)

using short8 = __attribute__((ext_vector_type(8))) short;
using f32x4  = __attribute__((ext_vector_type(4))) float;
using fl4    = __attribute__((ext_vector_type(4))) float;
using u16x4  = __attribute__((ext_vector_type(4))) unsigned short;

#define MFMA16(a, b, c) __builtin_amdgcn_mfma_f32_16x16x32_bf16((a), (b), (c), 0, 0, 0)

// 0.125 (1/sqrt(64)) * log2(e)
#define SCL2E 0.18033688011112042f

__device__ __forceinline__ float bf2f(unsigned short u) {
  union { unsigned int i; float f; } c;
  c.i = ((unsigned int)u) << 16;
  return c.f;
}
__device__ __forceinline__ unsigned short f2bf(float f) {
  union { float f; unsigned int i; } c;
  c.f = f;
  unsigned int x = c.i;
  return (unsigned short)((x + 0x7fffu + ((x >> 16) & 1u)) >> 16);  // RNE
}
__device__ __forceinline__ float u2f(unsigned u) {
  union { unsigned i; float f; } c;
  c.i = u;
  return c.f;
}

__device__ __forceinline__ void gload_lds16(const void* g, void* l) {
  __builtin_amdgcn_global_load_lds(
      (const __attribute__((address_space(1))) void*)g,
      (__attribute__((address_space(3))) void*)l, 16, 0, 0);
}

// ---------------------------------------------------------------- convert
__global__ void cvt_f32_bf16(const float* __restrict__ in,
                             unsigned short* __restrict__ out, int n4) {
  int i = blockIdx.x * blockDim.x + threadIdx.x;
  int stride = gridDim.x * blockDim.x;
  for (; i < n4; i += stride) {
    fl4 v = ((const fl4*)in)[i];
    u16x4 o;
    o[0] = f2bf(v[0]); o[1] = f2bf(v[1]); o[2] = f2bf(v[2]); o[3] = f2bf(v[3]);
    ((u16x4*)out)[i] = o;
  }
}

// 4 weight matrices -> bf16 + dist_emb -> padded bf16 [80][64], one launch.
// blocks 0..1023: weights; block 1024: demb.
__global__ void cvt_w4d(const float* __restrict__ w0, const float* __restrict__ w1,
                        const float* __restrict__ w2, const float* __restrict__ w3,
                        const float* __restrict__ de,
                        unsigned short* __restrict__ o0, unsigned short* __restrict__ o1,
                        unsigned short* __restrict__ o2, unsigned short* __restrict__ o3,
                        unsigned short* __restrict__ od) {
  if (blockIdx.x == 1024) {
    for (int i = threadIdx.x; i < 80 * 64; i += 256)
      od[i] = (i < 73 * 64) ? f2bf(de[i]) : (unsigned short)0;
    return;
  }
  const int which = blockIdx.x >> 8;
  const float* in = which == 0 ? w0 : which == 1 ? w1 : which == 2 ? w2 : w3;
  unsigned short* out = which == 0 ? o0 : which == 1 ? o1 : which == 2 ? o2 : o3;
  int i = (blockIdx.x & 255) * 256 + threadIdx.x;
#pragma unroll
  for (int it = 0; it < 4; ++it, i += 65536) {
    fl4 v = ((const fl4*)in)[i];
    u16x4 o;
    o[0] = f2bf(v[0]); o[1] = f2bf(v[1]); o[2] = f2bf(v[2]); o[3] = f2bf(v[3]);
    ((u16x4*)out)[i] = o;
  }
}

// ---------------------------------------------------------------- fused QKV GEMM
// r=0 Q = X@Wq^T (+bq), r=1 K = X@Wk^T (+bk), r=2 V = Wv@X^T (+bv, row)
// outputs written in attn-fragment-tiled per-(b,head) layouts (r8 epilogue).
__global__ __launch_bounds__(256)
void gemm_qkv3(const unsigned short* __restrict__ X,
               const unsigned short* __restrict__ Bq,
               const unsigned short* __restrict__ Bk,
               const unsigned short* __restrict__ Bv,
               const float* __restrict__ biq, const float* __restrict__ bik,
               const float* __restrict__ biv,
               unsigned short* __restrict__ Cq, unsigned short* __restrict__ Ck,
               unsigned short* __restrict__ Cv) {
  __shared__ unsigned short lA[128 * 32];
  __shared__ unsigned short lB[128 * 32];
  const int i = blockIdx.x;
  const int wgid = (i & 7) * 96 + (i >> 3);   // XCD-chunked (768 % 8 == 0)
  const int r = wgid >> 8;
  const int id = wgid & 255;
  int bm, bn;
  const unsigned short *Aa, *Bb;
  if (r == 2) {           // V: A=Wv rows (o=dglob), B=X rows (s-global)
    bm = (id >> 5) * 128; bn = (id & 31) * 128;
    Aa = Bv; Bb = X;
  } else {                // Q/K: A=X rows (s-global), B=W rows (dglob)
    bm = (id >> 3) * 128; bn = (id & 7) * 128;
    Aa = X; Bb = (r == 0) ? Bq : Bk;
  }
  const float* bias = (r == 0) ? biq : (r == 1) ? bik : biv;

  const int tid = threadIdx.x;
  const int wave = tid >> 6, lane = tid & 63;
  const int wm = wave >> 1, wn = wave & 1;

  f32x4 acc[4][4];
#pragma unroll
  for (int m = 0; m < 4; ++m)
#pragma unroll
    for (int n = 0; n < 4; ++n) acc[m][n] = (f32x4){0.f, 0.f, 0.f, 0.f};

  const int t0 = tid, t1 = tid + 256;
  const int ar0 = t0 >> 2, ak0 = (t0 & 3) * 8;
  const int ar1 = t1 >> 2, ak1 = (t1 & 3) * 8;
  const unsigned short* Ab = Aa + (size_t)bm * 1024;
  const unsigned short* Bbb = Bb + (size_t)bn * 1024;
  const int fr = lane & 15, fk = (lane >> 4) * 8;

  for (int kt = 0; kt < 1024; kt += 32) {
    gload_lds16(Ab + (size_t)ar0 * 1024 + kt + ak0, (void*)&lA[(wave * 64) * 8]);
    gload_lds16(Ab + (size_t)ar1 * 1024 + kt + ak1, (void*)&lA[2048 + (wave * 64) * 8]);
    gload_lds16(Bbb + (size_t)ar0 * 1024 + kt + ak0, (void*)&lB[(wave * 64) * 8]);
    gload_lds16(Bbb + (size_t)ar1 * 1024 + kt + ak1, (void*)&lB[2048 + (wave * 64) * 8]);
    __syncthreads();
    short8 af[4], bf[4];
#pragma unroll
    for (int m = 0; m < 4; ++m)
      af[m] = *(const short8*)&lA[(wm * 64 + m * 16 + fr) * 32 + fk];
#pragma unroll
    for (int n = 0; n < 4; ++n)
      bf[n] = *(const short8*)&lB[(wn * 64 + n * 16 + fr) * 32 + fk];
#pragma unroll
    for (int m = 0; m < 4; ++m)
#pragma unroll
      for (int n = 0; n < 4; ++n) acc[m][n] = MFMA16(af[m], bf[n], acc[m][n]);
    __syncthreads();
  }

  const int cr = (lane >> 4) * 4, cc = lane & 15;
#pragma unroll
  for (int m = 0; m < 4; ++m)
#pragma unroll
    for (int n = 0; n < 4; ++n) {
      const int col = bn + wn * 64 + n * 16 + cc;
#pragma unroll
      for (int g = 0; g < 4; ++g) {
        const int row = bm + wm * 64 + m * 16 + cr + g;
        if (r == 2) {
          // V: row = dglob, col = s-global
          const float v = acc[m][n][g] + bias[row];
          const int head = row >> 6, d = row & 63;
          const int b2 = col >> 10, sl = col & 1023, kk = sl & 31;
          size_t idx = ((size_t)((b2 << 4) + head) << 16) +
                       (size_t)(((sl >> 5) * 4 + (d >> 4)) * 512) +
                       (d & 15) * 32 + ((kk >> 3) * 8) + (kk & 7);
          Cv[idx] = f2bf(v);
        } else {
          // Q/K: row = s-global, col = dglob
          const float v = acc[m][n][g] + bias[col];
          const int head = col >> 6, d = col & 63;
          const int b2 = row >> 10, sl = row & 1023;
          const int dc = d >> 3;
          const size_t hb = (size_t)((b2 << 4) + head) << 16;
          if (r == 0) {
            size_t idx = hb +
                         (size_t)((((sl >> 4) * 2 + (dc >> 2)) * 16 + (sl & 15)) * 32) +
                         (dc & 3) * 8 + (d & 7);
            Cq[idx] = f2bf(v);
          } else {
            const int kt2 = sl >> 5;
            const int p = ((sl >> 3) & 3) * 4 + (sl & 3);
            const int half = (sl >> 2) & 1;
            size_t idx = hb +
                         (size_t)((((kt2 * 2 + half) * 2 + (dc >> 2)) * 512)) +
                         p * 32 + (dc & 3) * 8 + (d & 7);
            Ck[idx] = f2bf(v);
          }
        }
      }
    }
}

// ---------------------------------------------------------------- GEMM f32 out
__global__ __launch_bounds__(256)
void gemm_nt_f32(const unsigned short* __restrict__ A,
                 const unsigned short* __restrict__ B,
                 const float* __restrict__ bias, float* __restrict__ Cp) {
  __shared__ unsigned short lA[128 * 32];
  __shared__ unsigned short lB[128 * 32];
  const int i0 = blockIdx.x;
  const int wgid = (i0 & 7) * 32 + (i0 >> 3);  // XCD-chunked (256 % 8 == 0)
  const int bm = (wgid >> 3) * 128, bn = (wgid & 7) * 128;
  const int tid = threadIdx.x;
  const int wave = tid >> 6, lane = tid & 63;
  const int wm = wave >> 1, wn = wave & 1;

  f32x4 acc[4][4];
#pragma unroll
  for (int m = 0; m < 4; ++m)
#pragma unroll
    for (int n = 0; n < 4; ++n) acc[m][n] = (f32x4){0.f, 0.f, 0.f, 0.f};

  const int t0 = tid, t1 = tid + 256;
  const int ar0 = t0 >> 2, ak0 = (t0 & 3) * 8;
  const int ar1 = t1 >> 2, ak1 = (t1 & 3) * 8;
  const unsigned short* Ab = A + (size_t)bm * 1024;
  const unsigned short* Bb = B + (size_t)bn * 1024;
  const int fr = lane & 15, fk = (lane >> 4) * 8;

  for (int kt = 0; kt < 1024; kt += 32) {
    gload_lds16(Ab + (size_t)ar0 * 1024 + kt + ak0, (void*)&lA[(wave * 64) * 8]);
    gload_lds16(Ab + (size_t)ar1 * 1024 + kt + ak1, (void*)&lA[2048 + (wave * 64) * 8]);
    gload_lds16(Bb + (size_t)ar0 * 1024 + kt + ak0, (void*)&lB[(wave * 64) * 8]);
    gload_lds16(Bb + (size_t)ar1 * 1024 + kt + ak1, (void*)&lB[2048 + (wave * 64) * 8]);
    __syncthreads();
    short8 af[4], bf[4];
#pragma unroll
    for (int m = 0; m < 4; ++m)
      af[m] = *(const short8*)&lA[(wm * 64 + m * 16 + fr) * 32 + fk];
#pragma unroll
    for (int n = 0; n < 4; ++n)
      bf[n] = *(const short8*)&lB[(wn * 64 + n * 16 + fr) * 32 + fk];
#pragma unroll
    for (int m = 0; m < 4; ++m)
#pragma unroll
      for (int n = 0; n < 4; ++n) acc[m][n] = MFMA16(af[m], bf[n], acc[m][n]);
    __syncthreads();
  }

  const int cr = (lane >> 4) * 4, cc = lane & 15;
#pragma unroll
  for (int m = 0; m < 4; ++m)
#pragma unroll
    for (int n = 0; n < 4; ++n) {
      const int col = bn + wn * 64 + n * 16 + cc;
#pragma unroll
      for (int g = 0; g < 4; ++g) {
        const int row = bm + wm * 64 + m * 16 + cr + g;
        Cp[(size_t)row * 1024 + col] = acc[m][n][g] + bias[col];
      }
    }
}

// ---------------------------------------------------------------- attention
// Block = (b,h, 32 q-rows = groups A,B of 16). 4 waves split k (256 cols).
// All Q/K/V loads are dense 1KB wave loads from the tiled layouts.
// (round-8 version, verbatim)
__global__ __launch_bounds__(256, 2)
void attn_kernel(const unsigned short* __restrict__ q,
                 const unsigned short* __restrict__ k,
                 const unsigned short* __restrict__ vt,
                 const unsigned short* __restrict__ demb_bf,
                 float* __restrict__ probs,
                 unsigned short* __restrict__ ctx) {
  const int i = blockIdx.x;
  const int x = i & 7, s = i >> 3;            // 2048 blocks, 2048%8==0
  const int bh = ((s >> 5) << 3) + x;         // 32 same-XCD blocks share bh
  const int qseg = s & 31;
  const int hd = bh & 15, b = bh >> 4;
  const int tid = threadIdx.x, w = tid >> 6, lane = tid & 63;
  const int lq = lane & 15, Qr = lane >> 4;
  const int qA = qseg * 32, qB = qA + 16;

  __shared__ unsigned short qdc[32][78];   // bf16, PRE-SCALED by SCL2E
  __shared__ float reds[4][32];
  __shared__ float red[4][4][32][16];      // 32 KB partial PV

  const size_t hb = (size_t)((b << 4) + hd) << 16;  // per-(b,head) 64K u16 block
  const int lo16 = lq * 32 + Qr * 8;                // lane offset in 512-u16 block

  // Q frags (dense): Q''[qt][dcg][lq][dc2][8]
  const unsigned short* qh = q + hb + (size_t)(qseg * 4) * 512;
  short8 bqA0 = *(const short8*)(qh + lo16);
  short8 bqA1 = *(const short8*)(qh + 512 + lo16);
  short8 bqB0 = *(const short8*)(qh + 1024 + lo16);
  short8 bqB1 = *(const short8*)(qh + 1536 + lo16);

  // qd[q][p] = (Q[q] . dist_emb[p]) * SCL2E
  for (int pgq = w; pgq < 10; pgq += 4) {
    const int qblk = pgq >= 5;
    const int pg = qblk ? pgq - 5 : pgq;
    const unsigned short* dp = demb_bf + (size_t)(pg * 16 + lq) * 64 + Qr * 8;
    short8 a0 = *(const short8*)dp;
    short8 a1 = *(const short8*)(dp + 32);
    f32x4 c = (f32x4){0.f, 0.f, 0.f, 0.f};
    c = MFMA16(a0, qblk ? bqB0 : bqA0, c);
    c = MFMA16(a1, qblk ? bqB1 : bqA1, c);
#pragma unroll
    for (int g = 0; g < 4; ++g) {
      const int p = pg * 16 + Qr * 4 + g;
      if (p < 73) qdc[qblk * 16 + lq][p] = f2bf(c[g] * SCL2E);
    }
  }
  __syncthreads();

  const float qd0A = bf2f(qdc[lq][0]),       qd72A = bf2f(qdc[lq][72]);
  const float qd0B = bf2f(qdc[16 + lq][0]),  qd72B = bf2f(qdc[16 + lq][72]);

  float ssumA = 0.f, ssumB = 0.f;
  unsigned pafA[8][4], pafB[8][4];
  f32x4 oA0 = (f32x4){0.f, 0.f, 0.f, 0.f}, oA1 = oA0, oA2 = oA0, oA3 = oA0;
  f32x4 oB0 = oA0, oB1 = oA0, oB2 = oA0, oB3 = oA0;

  // K''[kt][half][dcg]: tile base = kt*2048; V''[vt2][db]: tile base = vt2*2048
  const unsigned short* kh = k + hb + (size_t)(w * 8) * 2048 + lo16;
  const unsigned short* vh = vt + hb + (size_t)(w * 8) * 2048 + lo16;

#pragma unroll
  for (int t = 0; t < 8; ++t) {
    const unsigned short* kp = kh + t * 2048;
    short8 ae0 = *(const short8*)kp;
    short8 ae1 = *(const short8*)(kp + 512);
    short8 ao0 = *(const short8*)(kp + 1024);
    short8 ao1 = *(const short8*)(kp + 1536);
    const unsigned short* vp = vh + t * 2048;
    short8 v0 = *(const short8*)vp;
    short8 v1 = *(const short8*)(vp + 512);
    short8 v2 = *(const short8*)(vp + 1024);
    short8 v3 = *(const short8*)(vp + 1536);

    f32x4 seA = (f32x4){0.f, 0.f, 0.f, 0.f}, soA = seA, seB = seA, soB = seA;
    seA = MFMA16(ae0, bqA0, seA); seA = MFMA16(ae1, bqA1, seA);
    soA = MFMA16(ao0, bqA0, soA); soA = MFMA16(ao1, bqA1, soA);
    seB = MFMA16(ae0, bqB0, seB); seB = MFMA16(ae1, bqB1, seB);
    soB = MFMA16(ao0, bqB0, soB); soB = MFMA16(ao1, bqB1, soB);

    const int tglob = w * 8 + t;
    // ---- group A
    {
      float pe[4], po[4];
      if (tglob * 32 + 31 < qA - 64) {
#pragma unroll
        for (int g = 0; g < 4; ++g) {
          pe[g] = exp2f(fmaf(seA[g], SCL2E, qd0A));
          po[g] = exp2f(fmaf(soA[g], SCL2E, qd0A));
        }
      } else if (tglob * 32 > qA + 23) {
#pragma unroll
        for (int g = 0; g < 4; ++g) {
          pe[g] = exp2f(fmaf(seA[g], SCL2E, qd72A));
          po[g] = exp2f(fmaf(soA[g], SCL2E, qd72A));
        }
      } else {
        const int c0 = tglob * 32 + Qr * 8 - (qA + lq);
#pragma unroll
        for (int g = 0; g < 4; ++g) {
          int d0 = c0 + g;     d0 = d0 < -64 ? -64 : (d0 > 8 ? 8 : d0);
          int d1 = c0 + 4 + g; d1 = d1 < -64 ? -64 : (d1 > 8 ? 8 : d1);
          pe[g] = exp2f(fmaf(seA[g], SCL2E, bf2f(qdc[lq][d0 + 64])));
          po[g] = exp2f(fmaf(soA[g], SCL2E, bf2f(qdc[lq][d1 + 64])));
        }
      }
#pragma unroll
      for (int g = 0; g < 4; ++g) ssumA += pe[g] + po[g];
      asm("v_cvt_pk_bf16_f32 %0, %1, %2" : "=v"(pafA[t][0]) : "v"(pe[0]), "v"(pe[1]));
      asm("v_cvt_pk_bf16_f32 %0, %1, %2" : "=v"(pafA[t][1]) : "v"(pe[2]), "v"(pe[3]));
      asm("v_cvt_pk_bf16_f32 %0, %1, %2" : "=v"(pafA[t][2]) : "v"(po[0]), "v"(po[1]));
      asm("v_cvt_pk_bf16_f32 %0, %1, %2" : "=v"(pafA[t][3]) : "v"(po[2]), "v"(po[3]));
      union { unsigned u[4]; short8 s8v; } uu;
      uu.u[0] = pafA[t][0]; uu.u[1] = pafA[t][1];
      uu.u[2] = pafA[t][2]; uu.u[3] = pafA[t][3];
      const short8 pa = uu.s8v;
      oA0 = MFMA16(pa, v0, oA0);
      oA1 = MFMA16(pa, v1, oA1);
      oA2 = MFMA16(pa, v2, oA2);
      oA3 = MFMA16(pa, v3, oA3);
    }
    // ---- group B
    {
      float pe[4], po[4];
      if (tglob * 32 + 31 < qB - 64) {
#pragma unroll
        for (int g = 0; g < 4; ++g) {
          pe[g] = exp2f(fmaf(seB[g], SCL2E, qd0B));
          po[g] = exp2f(fmaf(soB[g], SCL2E, qd0B));
        }
      } else if (tglob * 32 > qB + 23) {
#pragma unroll
        for (int g = 0; g < 4; ++g) {
          pe[g] = exp2f(fmaf(seB[g], SCL2E, qd72B));
          po[g] = exp2f(fmaf(soB[g], SCL2E, qd72B));
        }
      } else {
        const int c0 = tglob * 32 + Qr * 8 - (qB + lq);
#pragma unroll
        for (int g = 0; g < 4; ++g) {
          int d0 = c0 + g;     d0 = d0 < -64 ? -64 : (d0 > 8 ? 8 : d0);
          int d1 = c0 + 4 + g; d1 = d1 < -64 ? -64 : (d1 > 8 ? 8 : d1);
          pe[g] = exp2f(fmaf(seB[g], SCL2E, bf2f(qdc[16 + lq][d0 + 64])));
          po[g] = exp2f(fmaf(soB[g], SCL2E, bf2f(qdc[16 + lq][d1 + 64])));
        }
      }
#pragma unroll
      for (int g = 0; g < 4; ++g) ssumB += pe[g] + po[g];
      asm("v_cvt_pk_bf16_f32 %0, %1, %2" : "=v"(pafB[t][0]) : "v"(pe[0]), "v"(pe[1]));
      asm("v_cvt_pk_bf16_f32 %0, %1, %2" : "=v"(pafB[t][1]) : "v"(pe[2]), "v"(pe[3]));
      asm("v_cvt_pk_bf16_f32 %0, %1, %2" : "=v"(pafB[t][2]) : "v"(po[0]), "v"(po[1]));
      asm("v_cvt_pk_bf16_f32 %0, %1, %2" : "=v"(pafB[t][3]) : "v"(po[2]), "v"(po[3]));
      union { unsigned u[4]; short8 s8v; } uu;
      uu.u[0] = pafB[t][0]; uu.u[1] = pafB[t][1];
      uu.u[2] = pafB[t][2]; uu.u[3] = pafB[t][3];
      const short8 pa = uu.s8v;
      oB0 = MFMA16(pa, v0, oB0);
      oB1 = MFMA16(pa, v1, oB1);
      oB2 = MFMA16(pa, v2, oB2);
      oB3 = MFMA16(pa, v3, oB3);
    }
  }
  ssumA += __shfl_xor(ssumA, 16, 64);
  ssumA += __shfl_xor(ssumA, 32, 64);
  ssumB += __shfl_xor(ssumB, 16, 64);
  ssumB += __shfl_xor(ssumB, 32, 64);
  if (lane < 16) {
    reds[w][lane] = ssumA;
    reds[w][16 + lane] = ssumB;
  }
#pragma unroll
  for (int g = 0; g < 4; ++g) {
    red[w][0][Qr * 4 + g][lq] = oA0[g];
    red[w][1][Qr * 4 + g][lq] = oA1[g];
    red[w][2][Qr * 4 + g][lq] = oA2[g];
    red[w][3][Qr * 4 + g][lq] = oA3[g];
    red[w][0][16 + Qr * 4 + g][lq] = oB0[g];
    red[w][1][16 + Qr * 4 + g][lq] = oB1[g];
    red[w][2][16 + Qr * 4 + g][lq] = oB2[g];
    red[w][3][16 + Qr * 4 + g][lq] = oB3[g];
  }
  __syncthreads();

  const float invA =
      1.0f / (reds[0][lq] + reds[1][lq] + reds[2][lq] + reds[3][lq]);
  const float invB = 1.0f / (reds[0][16 + lq] + reds[1][16 + lq] +
                             reds[2][16 + lq] + reds[3][16 + lq]);
  float* prowA = probs + ((size_t)bh * 1024 + qA + lq) * 1024 + w * 256 + Qr * 8;
  float* prowB = prowA + (size_t)16 * 1024;
#pragma unroll
  for (int t = 0; t < 8; ++t) {
    f32x4 p0, p1;
    p0[0] = u2f(pafA[t][0] << 16) * invA;
    p0[1] = u2f(pafA[t][0] & 0xffff0000u) * invA;
    p0[2] = u2f(pafA[t][1] << 16) * invA;
    p0[3] = u2f(pafA[t][1] & 0xffff0000u) * invA;
    p1[0] = u2f(pafA[t][2] << 16) * invA;
    p1[1] = u2f(pafA[t][2] & 0xffff0000u) * invA;
    p1[2] = u2f(pafA[t][3] << 16) * invA;
    p1[3] = u2f(pafA[t][3] & 0xffff0000u) * invA;
    *(f32x4*)&prowA[t * 32] = p0;
    *(f32x4*)&prowA[t * 32 + 4] = p1;
    f32x4 q0, q1;
    q0[0] = u2f(pafB[t][0] << 16) * invB;
    q0[1] = u2f(pafB[t][0] & 0xffff0000u) * invB;
    q0[2] = u2f(pafB[t][1] << 16) * invB;
    q0[3] = u2f(pafB[t][1] & 0xffff0000u) * invB;
    q1[0] = u2f(pafB[t][2] << 16) * invB;
    q1[1] = u2f(pafB[t][2] & 0xffff0000u) * invB;
    q1[2] = u2f(pafB[t][3] << 16) * invB;
    q1[3] = u2f(pafB[t][3] & 0xffff0000u) * invB;
    *(f32x4*)&prowB[t * 32] = q0;
    *(f32x4*)&prowB[t * 32 + 4] = q1;
  }

  // ctx: thread -> q = tid>>3 (0..31), d = (tid&7)*8 + j
  {
    const int qrow = tid >> 3;
    const int d0 = (tid & 7) * 8;
    const float invq = 1.0f / (reds[0][qrow] + reds[1][qrow] +
                               reds[2][qrow] + reds[3][qrow]);
    u16x4 cv0, cv1;
#pragma unroll
    for (int j = 0; j < 8; ++j) {
      const int d = d0 + j;
      const int db = d >> 4, dd = d & 15;
      float sum = red[0][db][qrow][dd] + red[1][db][qrow][dd] +
                  red[2][db][qrow][dd] + red[3][db][qrow][dd];
      if (j < 4) cv0[j] = f2bf(sum * invq);
      else       cv1[j - 4] = f2bf(sum * invq);
    }
    unsigned short* cb =
        ctx + ((size_t)(b * 1024 + qA + qrow)) * 1024 + hd * 64 + d0;
    *(u16x4*)cb = cv0;
    *(u16x4*)(cb + 4) = cv1;
  }
}

// ---------------------------------------------------------------- launch
extern "C" void kernel_launch(void* const* d_in, const int* in_sizes, int n_in,
                              void* d_out, int out_size, void* d_ws, size_t ws_size,
                              hipStream_t stream) {
  const float* hs = (const float*)d_in[0];
  const float* Wq = (const float*)d_in[1];
  const float* bq = (const float*)d_in[2];
  const float* Wk = (const float*)d_in[3];
  const float* bk = (const float*)d_in[4];
  const float* Wv = (const float*)d_in[5];
  const float* bv = (const float*)d_in[6];
  const float* Wo = (const float*)d_in[7];
  const float* bo = (const float*)d_in[8];
  const float* de = (const float*)d_in[9];

  float* out = (float*)d_out;
  float* probs = out + (size_t)4 * 1024 * 1024;

  char* ws = (char*)d_ws;
  unsigned short* Xb  = (unsigned short*)(ws);                      // -> ctx later
  unsigned short* Wqb = (unsigned short*)(ws + ((size_t)8 << 20));
  unsigned short* Wkb = (unsigned short*)(ws + ((size_t)10 << 20));
  unsigned short* Wvb = (unsigned short*)(ws + ((size_t)12 << 20));
  unsigned short* Wob = (unsigned short*)(ws + ((size_t)14 << 20));
  unsigned short* Qb  = (unsigned short*)(ws + ((size_t)16 << 20));
  unsigned short* Kb  = (unsigned short*)(ws + ((size_t)24 << 20));
  unsigned short* Vt  = (unsigned short*)(ws + ((size_t)32 << 20));
  unsigned short* Db  = (unsigned short*)(ws + ((size_t)40 << 20));  // own slot
  unsigned short* Cx  = Xb;   // ctx (after QKV gemm; X dead)

  cvt_f32_bf16<<<dim3(1024), dim3(256), 0, stream>>>(hs, Xb, (4 * 1024 * 1024) / 4);
  cvt_w4d<<<dim3(1025), dim3(256), 0, stream>>>(Wq, Wk, Wv, Wo, de,
                                                Wqb, Wkb, Wvb, Wob, Db);

  gemm_qkv3<<<dim3(768), dim3(256), 0, stream>>>(Xb, Wqb, Wkb, Wvb, bq, bk, bv,
                                                 Qb, Kb, Vt);

  attn_kernel<<<dim3(2048), dim3(256), 0, stream>>>(Qb, Kb, Vt, Db, probs, Cx);

  gemm_nt_f32<<<dim3(256), dim3(256), 0, stream>>>(Cx, Wob, bo, out);
}

// Round 13
// 173.785 us; speedup vs baseline: 1.3790x; 1.0483x over previous
//
#include <hip/hip_runtime.h>

// Wav2Vec2BertSelfAttention on MI355X (gfx950)
// B=4, S=1024, HID=1024, NH=16, HD=64, LEFT=64, RIGHT=8, NUM_POS=73
//
// Round 13: r8 pipeline + attn PHASE-SPLIT: loop1 = K-load/QK/exp/pack(paf),
// loop2 = V-load/PV + fused normalized probs stores. P stays in registers;
// one extra barrier buys independent iterations in both loops (deep load
// hoisting) and spreads the 268MB store stream across loop2.
//   Q''[qt][dcg][lq][dc2][8]   K''[kt][half][dcg][p][dc2][8]
//   V''[vt2][db][lq][Qr][8]   (per (b,head) 128KB blocks, dense 1KB loads)

using short8 = __attribute__((ext_vector_type(8))) short;
using f32x4  = __attribute__((ext_vector_type(4))) float;
using fl4    = __attribute__((ext_vector_type(4))) float;
using u16x4  = __attribute__((ext_vector_type(4))) unsigned short;

#define MFMA16(a, b, c) __builtin_amdgcn_mfma_f32_16x16x32_bf16((a), (b), (c), 0, 0, 0)

// 0.125 (1/sqrt(64)) * log2(e)
#define SCL2E 0.18033688011112042f

__device__ __forceinline__ float bf2f(unsigned short u) {
  union { unsigned int i; float f; } c;
  c.i = ((unsigned int)u) << 16;
  return c.f;
}
__device__ __forceinline__ unsigned short f2bf(float f) {
  union { float f; unsigned int i; } c;
  c.f = f;
  unsigned int x = c.i;
  return (unsigned short)((x + 0x7fffu + ((x >> 16) & 1u)) >> 16);  // RNE
}
__device__ __forceinline__ float u2f(unsigned u) {
  union { unsigned i; float f; } c;
  c.i = u;
  return c.f;
}

__device__ __forceinline__ void gload_lds16(const void* g, void* l) {
  __builtin_amdgcn_global_load_lds(
      (const __attribute__((address_space(1))) void*)g,
      (__attribute__((address_space(3))) void*)l, 16, 0, 0);
}

// ---------------------------------------------------------------- convert
__global__ void cvt_f32_bf16(const float* __restrict__ in,
                             unsigned short* __restrict__ out, int n4) {
  int i = blockIdx.x * blockDim.x + threadIdx.x;
  int stride = gridDim.x * blockDim.x;
  for (; i < n4; i += stride) {
    fl4 v = ((const fl4*)in)[i];
    u16x4 o;
    o[0] = f2bf(v[0]); o[1] = f2bf(v[1]); o[2] = f2bf(v[2]); o[3] = f2bf(v[3]);
    ((u16x4*)out)[i] = o;
  }
}

// 4 weight matrices -> bf16 + dist_emb -> padded bf16 [80][64], one launch.
__global__ void cvt_w4d(const float* __restrict__ w0, const float* __restrict__ w1,
                        const float* __restrict__ w2, const float* __restrict__ w3,
                        const float* __restrict__ de,
                        unsigned short* __restrict__ o0, unsigned short* __restrict__ o1,
                        unsigned short* __restrict__ o2, unsigned short* __restrict__ o3,
                        unsigned short* __restrict__ od) {
  if (blockIdx.x == 1024) {
    for (int i = threadIdx.x; i < 80 * 64; i += 256)
      od[i] = (i < 73 * 64) ? f2bf(de[i]) : (unsigned short)0;
    return;
  }
  const int which = blockIdx.x >> 8;
  const float* in = which == 0 ? w0 : which == 1 ? w1 : which == 2 ? w2 : w3;
  unsigned short* out = which == 0 ? o0 : which == 1 ? o1 : which == 2 ? o2 : o3;
  int i = (blockIdx.x & 255) * 256 + threadIdx.x;
#pragma unroll
  for (int it = 0; it < 4; ++it, i += 65536) {
    fl4 v = ((const fl4*)in)[i];
    u16x4 o;
    o[0] = f2bf(v[0]); o[1] = f2bf(v[1]); o[2] = f2bf(v[2]); o[3] = f2bf(v[3]);
    ((u16x4*)out)[i] = o;
  }
}

// ---------------------------------------------------------------- fused QKV GEMM
// r=0 Q = X@Wq^T (+bq), r=1 K = X@Wk^T (+bk), r=2 V = Wv@X^T (+bv, row)
// outputs written in attn-fragment-tiled per-(b,head) layouts (r8 epilogue).
__global__ __launch_bounds__(256)
void gemm_qkv3(const unsigned short* __restrict__ X,
               const unsigned short* __restrict__ Bq,
               const unsigned short* __restrict__ Bk,
               const unsigned short* __restrict__ Bv,
               const float* __restrict__ biq, const float* __restrict__ bik,
               const float* __restrict__ biv,
               unsigned short* __restrict__ Cq, unsigned short* __restrict__ Ck,
               unsigned short* __restrict__ Cv) {
  __shared__ unsigned short lA[128 * 32];
  __shared__ unsigned short lB[128 * 32];
  const int i = blockIdx.x;
  const int wgid = (i & 7) * 96 + (i >> 3);   // XCD-chunked (768 % 8 == 0)
  const int r = wgid >> 8;
  const int id = wgid & 255;
  int bm, bn;
  const unsigned short *Aa, *Bb;
  if (r == 2) {           // V: A=Wv rows (o=dglob), B=X rows (s-global)
    bm = (id >> 5) * 128; bn = (id & 31) * 128;
    Aa = Bv; Bb = X;
  } else {                // Q/K: A=X rows (s-global), B=W rows (dglob)
    bm = (id >> 3) * 128; bn = (id & 7) * 128;
    Aa = X; Bb = (r == 0) ? Bq : Bk;
  }
  const float* bias = (r == 0) ? biq : (r == 1) ? bik : biv;

  const int tid = threadIdx.x;
  const int wave = tid >> 6, lane = tid & 63;
  const int wm = wave >> 1, wn = wave & 1;

  f32x4 acc[4][4];
#pragma unroll
  for (int m = 0; m < 4; ++m)
#pragma unroll
    for (int n = 0; n < 4; ++n) acc[m][n] = (f32x4){0.f, 0.f, 0.f, 0.f};

  const int t0 = tid, t1 = tid + 256;
  const int ar0 = t0 >> 2, ak0 = (t0 & 3) * 8;
  const int ar1 = t1 >> 2, ak1 = (t1 & 3) * 8;
  const unsigned short* Ab = Aa + (size_t)bm * 1024;
  const unsigned short* Bbb = Bb + (size_t)bn * 1024;
  const int fr = lane & 15, fk = (lane >> 4) * 8;

  for (int kt = 0; kt < 1024; kt += 32) {
    gload_lds16(Ab + (size_t)ar0 * 1024 + kt + ak0, (void*)&lA[(wave * 64) * 8]);
    gload_lds16(Ab + (size_t)ar1 * 1024 + kt + ak1, (void*)&lA[2048 + (wave * 64) * 8]);
    gload_lds16(Bbb + (size_t)ar0 * 1024 + kt + ak0, (void*)&lB[(wave * 64) * 8]);
    gload_lds16(Bbb + (size_t)ar1 * 1024 + kt + ak1, (void*)&lB[2048 + (wave * 64) * 8]);
    __syncthreads();
    short8 af[4], bf[4];
#pragma unroll
    for (int m = 0; m < 4; ++m)
      af[m] = *(const short8*)&lA[(wm * 64 + m * 16 + fr) * 32 + fk];
#pragma unroll
    for (int n = 0; n < 4; ++n)
      bf[n] = *(const short8*)&lB[(wn * 64 + n * 16 + fr) * 32 + fk];
#pragma unroll
    for (int m = 0; m < 4; ++m)
#pragma unroll
      for (int n = 0; n < 4; ++n) acc[m][n] = MFMA16(af[m], bf[n], acc[m][n]);
    __syncthreads();
  }

  const int cr = (lane >> 4) * 4, cc = lane & 15;
#pragma unroll
  for (int m = 0; m < 4; ++m)
#pragma unroll
    for (int n = 0; n < 4; ++n) {
      const int col = bn + wn * 64 + n * 16 + cc;
#pragma unroll
      for (int g = 0; g < 4; ++g) {
        const int row = bm + wm * 64 + m * 16 + cr + g;
        if (r == 2) {
          // V: row = dglob, col = s-global
          const float v = acc[m][n][g] + bias[row];
          const int head = row >> 6, d = row & 63;
          const int b2 = col >> 10, sl = col & 1023, kk = sl & 31;
          size_t idx = ((size_t)((b2 << 4) + head) << 16) +
                       (size_t)(((sl >> 5) * 4 + (d >> 4)) * 512) +
                       (d & 15) * 32 + ((kk >> 3) * 8) + (kk & 7);
          Cv[idx] = f2bf(v);
        } else {
          // Q/K: row = s-global, col = dglob
          const float v = acc[m][n][g] + bias[col];
          const int head = col >> 6, d = col & 63;
          const int b2 = row >> 10, sl = row & 1023;
          const int dc = d >> 3;
          const size_t hb = (size_t)((b2 << 4) + head) << 16;
          if (r == 0) {
            size_t idx = hb +
                         (size_t)((((sl >> 4) * 2 + (dc >> 2)) * 16 + (sl & 15)) * 32) +
                         (dc & 3) * 8 + (d & 7);
            Cq[idx] = f2bf(v);
          } else {
            const int kt2 = sl >> 5;
            const int p = ((sl >> 3) & 3) * 4 + (sl & 3);
            const int half = (sl >> 2) & 1;
            size_t idx = hb +
                         (size_t)((((kt2 * 2 + half) * 2 + (dc >> 2)) * 512)) +
                         p * 32 + (dc & 3) * 8 + (d & 7);
            Ck[idx] = f2bf(v);
          }
        }
      }
    }
}

// ---------------------------------------------------------------- GEMM f32 out
__global__ __launch_bounds__(256)
void gemm_nt_f32(const unsigned short* __restrict__ A,
                 const unsigned short* __restrict__ B,
                 const float* __restrict__ bias, float* __restrict__ Cp) {
  __shared__ unsigned short lA[128 * 32];
  __shared__ unsigned short lB[128 * 32];
  const int tid = threadIdx.x;
  const int wave = tid >> 6, lane = tid & 63;
  const int wm = wave >> 1, wn = wave & 1;
  const int bm = blockIdx.x * 128, bn = blockIdx.y * 128;

  f32x4 acc[4][4];
#pragma unroll
  for (int m = 0; m < 4; ++m)
#pragma unroll
    for (int n = 0; n < 4; ++n) acc[m][n] = (f32x4){0.f, 0.f, 0.f, 0.f};

  const int t0 = tid, t1 = tid + 256;
  const int ar0 = t0 >> 2, ak0 = (t0 & 3) * 8;
  const int ar1 = t1 >> 2, ak1 = (t1 & 3) * 8;
  const unsigned short* Ab = A + (size_t)bm * 1024;
  const unsigned short* Bb = B + (size_t)bn * 1024;
  const int fr = lane & 15, fk = (lane >> 4) * 8;

  for (int kt = 0; kt < 1024; kt += 32) {
    gload_lds16(Ab + (size_t)ar0 * 1024 + kt + ak0, (void*)&lA[(wave * 64) * 8]);
    gload_lds16(Ab + (size_t)ar1 * 1024 + kt + ak1, (void*)&lA[2048 + (wave * 64) * 8]);
    gload_lds16(Bb + (size_t)ar0 * 1024 + kt + ak0, (void*)&lB[(wave * 64) * 8]);
    gload_lds16(Bb + (size_t)ar1 * 1024 + kt + ak1, (void*)&lB[2048 + (wave * 64) * 8]);
    __syncthreads();
    short8 af[4], bf[4];
#pragma unroll
    for (int m = 0; m < 4; ++m)
      af[m] = *(const short8*)&lA[(wm * 64 + m * 16 + fr) * 32 + fk];
#pragma unroll
    for (int n = 0; n < 4; ++n)
      bf[n] = *(const short8*)&lB[(wn * 64 + n * 16 + fr) * 32 + fk];
#pragma unroll
    for (int m = 0; m < 4; ++m)
#pragma unroll
      for (int n = 0; n < 4; ++n) acc[m][n] = MFMA16(af[m], bf[n], acc[m][n]);
    __syncthreads();
  }

  const int cr = (lane >> 4) * 4, cc = lane & 15;
#pragma unroll
  for (int m = 0; m < 4; ++m)
#pragma unroll
    for (int n = 0; n < 4; ++n) {
      const int col = bn + wn * 64 + n * 16 + cc;
#pragma unroll
      for (int g = 0; g < 4; ++g) {
        const int row = bm + wm * 64 + m * 16 + cr + g;
        Cp[(size_t)row * 1024 + col] = acc[m][n][g] + bias[col];
      }
    }
}

// ---------------------------------------------------------------- attention
// Block = (b,h, 32 q-rows = groups A,B of 16). 4 waves split k (256 cols).
// PHASE-SPLIT: loop1 K/QK/exp/pack -> paf regs; barrier (reds); loop2 V/PV +
// fused normalized probs stores; barrier (red); ctx reduce.
__global__ __launch_bounds__(256, 2)
void attn_kernel(const unsigned short* __restrict__ q,
                 const unsigned short* __restrict__ k,
                 const unsigned short* __restrict__ vt,
                 const unsigned short* __restrict__ demb_bf,
                 float* __restrict__ probs,
                 unsigned short* __restrict__ ctx) {
  const int i = blockIdx.x;
  const int x = i & 7, s = i >> 3;            // 2048 blocks, 2048%8==0
  const int bh = ((s >> 5) << 3) + x;         // 32 same-XCD blocks share bh
  const int qseg = s & 31;
  const int hd = bh & 15, b = bh >> 4;
  const int tid = threadIdx.x, w = tid >> 6, lane = tid & 63;
  const int lq = lane & 15, Qr = lane >> 4;
  const int qA = qseg * 32, qB = qA + 16;

  __shared__ unsigned short qdc[32][78];   // bf16, PRE-SCALED by SCL2E
  __shared__ float reds[4][32];
  __shared__ float red[4][4][32][16];      // 32 KB partial PV

  const size_t hb = (size_t)((b << 4) + hd) << 16;  // per-(b,head) 64K u16 block
  const int lo16 = lq * 32 + Qr * 8;                // lane offset in 512-u16 block

  // Q frags (dense): Q''[qt][dcg][lq][dc2][8]
  const unsigned short* qh = q + hb + (size_t)(qseg * 4) * 512;
  short8 bqA0 = *(const short8*)(qh + lo16);
  short8 bqA1 = *(const short8*)(qh + 512 + lo16);
  short8 bqB0 = *(const short8*)(qh + 1024 + lo16);
  short8 bqB1 = *(const short8*)(qh + 1536 + lo16);

  // qd[q][p] = (Q[q] . dist_emb[p]) * SCL2E
  for (int pgq = w; pgq < 10; pgq += 4) {
    const int qblk = pgq >= 5;
    const int pg = qblk ? pgq - 5 : pgq;
    const unsigned short* dp = demb_bf + (size_t)(pg * 16 + lq) * 64 + Qr * 8;
    short8 a0 = *(const short8*)dp;
    short8 a1 = *(const short8*)(dp + 32);
    f32x4 c = (f32x4){0.f, 0.f, 0.f, 0.f};
    c = MFMA16(a0, qblk ? bqB0 : bqA0, c);
    c = MFMA16(a1, qblk ? bqB1 : bqA1, c);
#pragma unroll
    for (int g = 0; g < 4; ++g) {
      const int p = pg * 16 + Qr * 4 + g;
      if (p < 73) qdc[qblk * 16 + lq][p] = f2bf(c[g] * SCL2E);
    }
  }
  __syncthreads();

  const float qd0A = bf2f(qdc[lq][0]),       qd72A = bf2f(qdc[lq][72]);
  const float qd0B = bf2f(qdc[16 + lq][0]),  qd72B = bf2f(qdc[16 + lq][72]);

  float ssumA = 0.f, ssumB = 0.f;
  unsigned pafA[8][4], pafB[8][4];

  const unsigned short* kh = k + hb + (size_t)(w * 8) * 2048 + lo16;
  const unsigned short* vh = vt + hb + (size_t)(w * 8) * 2048 + lo16;

  // ---------------- phase 1: K loads + QK + exp + pack (independent iters)
#pragma unroll
  for (int t = 0; t < 8; ++t) {
    const unsigned short* kp = kh + t * 2048;
    short8 ae0 = *(const short8*)kp;
    short8 ae1 = *(const short8*)(kp + 512);
    short8 ao0 = *(const short8*)(kp + 1024);
    short8 ao1 = *(const short8*)(kp + 1536);

    f32x4 seA = (f32x4){0.f, 0.f, 0.f, 0.f}, soA = seA, seB = seA, soB = seA;
    seA = MFMA16(ae0, bqA0, seA); seA = MFMA16(ae1, bqA1, seA);
    soA = MFMA16(ao0, bqA0, soA); soA = MFMA16(ao1, bqA1, soA);
    seB = MFMA16(ae0, bqB0, seB); seB = MFMA16(ae1, bqB1, seB);
    soB = MFMA16(ao0, bqB0, soB); soB = MFMA16(ao1, bqB1, soB);

    const int tglob = w * 8 + t;
    // ---- group A
    {
      float pe[4], po[4];
      if (tglob * 32 + 31 < qA - 64) {
#pragma unroll
        for (int g = 0; g < 4; ++g) {
          pe[g] = exp2f(fmaf(seA[g], SCL2E, qd0A));
          po[g] = exp2f(fmaf(soA[g], SCL2E, qd0A));
        }
      } else if (tglob * 32 > qA + 23) {
#pragma unroll
        for (int g = 0; g < 4; ++g) {
          pe[g] = exp2f(fmaf(seA[g], SCL2E, qd72A));
          po[g] = exp2f(fmaf(soA[g], SCL2E, qd72A));
        }
      } else {
        const int c0 = tglob * 32 + Qr * 8 - (qA + lq);
#pragma unroll
        for (int g = 0; g < 4; ++g) {
          int d0 = c0 + g;     d0 = d0 < -64 ? -64 : (d0 > 8 ? 8 : d0);
          int d1 = c0 + 4 + g; d1 = d1 < -64 ? -64 : (d1 > 8 ? 8 : d1);
          pe[g] = exp2f(fmaf(seA[g], SCL2E, bf2f(qdc[lq][d0 + 64])));
          po[g] = exp2f(fmaf(soA[g], SCL2E, bf2f(qdc[lq][d1 + 64])));
        }
      }
#pragma unroll
      for (int g = 0; g < 4; ++g) ssumA += pe[g] + po[g];
      asm("v_cvt_pk_bf16_f32 %0, %1, %2" : "=v"(pafA[t][0]) : "v"(pe[0]), "v"(pe[1]));
      asm("v_cvt_pk_bf16_f32 %0, %1, %2" : "=v"(pafA[t][1]) : "v"(pe[2]), "v"(pe[3]));
      asm("v_cvt_pk_bf16_f32 %0, %1, %2" : "=v"(pafA[t][2]) : "v"(po[0]), "v"(po[1]));
      asm("v_cvt_pk_bf16_f32 %0, %1, %2" : "=v"(pafA[t][3]) : "v"(po[2]), "v"(po[3]));
    }
    // ---- group B
    {
      float pe[4], po[4];
      if (tglob * 32 + 31 < qB - 64) {
#pragma unroll
        for (int g = 0; g < 4; ++g) {
          pe[g] = exp2f(fmaf(seB[g], SCL2E, qd0B));
          po[g] = exp2f(fmaf(soB[g], SCL2E, qd0B));
        }
      } else if (tglob * 32 > qB + 23) {
#pragma unroll
        for (int g = 0; g < 4; ++g) {
          pe[g] = exp2f(fmaf(seB[g], SCL2E, qd72B));
          po[g] = exp2f(fmaf(soB[g], SCL2E, qd72B));
        }
      } else {
        const int c0 = tglob * 32 + Qr * 8 - (qB + lq);
#pragma unroll
        for (int g = 0; g < 4; ++g) {
          int d0 = c0 + g;     d0 = d0 < -64 ? -64 : (d0 > 8 ? 8 : d0);
          int d1 = c0 + 4 + g; d1 = d1 < -64 ? -64 : (d1 > 8 ? 8 : d1);
          pe[g] = exp2f(fmaf(seB[g], SCL2E, bf2f(qdc[16 + lq][d0 + 64])));
          po[g] = exp2f(fmaf(soB[g], SCL2E, bf2f(qdc[16 + lq][d1 + 64])));
        }
      }
#pragma unroll
      for (int g = 0; g < 4; ++g) ssumB += pe[g] + po[g];
      asm("v_cvt_pk_bf16_f32 %0, %1, %2" : "=v"(pafB[t][0]) : "v"(pe[0]), "v"(pe[1]));
      asm("v_cvt_pk_bf16_f32 %0, %1, %2" : "=v"(pafB[t][1]) : "v"(pe[2]), "v"(pe[3]));
      asm("v_cvt_pk_bf16_f32 %0, %1, %2" : "=v"(pafB[t][2]) : "v"(po[0]), "v"(po[1]));
      asm("v_cvt_pk_bf16_f32 %0, %1, %2" : "=v"(pafB[t][3]) : "v"(po[2]), "v"(po[3]));
    }
  }
  ssumA += __shfl_xor(ssumA, 16, 64);
  ssumA += __shfl_xor(ssumA, 32, 64);
  ssumB += __shfl_xor(ssumB, 16, 64);
  ssumB += __shfl_xor(ssumB, 32, 64);
  if (lane < 16) {
    reds[w][lane] = ssumA;
    reds[w][16 + lane] = ssumB;
  }
  __syncthreads();  // reds ready -> normalization available in phase 2

  const float invA =
      1.0f / (reds[0][lq] + reds[1][lq] + reds[2][lq] + reds[3][lq]);
  const float invB = 1.0f / (reds[0][16 + lq] + reds[1][16 + lq] +
                             reds[2][16 + lq] + reds[3][16 + lq]);
  float* prowA = probs + ((size_t)bh * 1024 + qA + lq) * 1024 + w * 256 + Qr * 8;
  float* prowB = prowA + (size_t)16 * 1024;

  // ---------------- phase 2: V loads + PV + fused normalized probs stores
  f32x4 oA0 = (f32x4){0.f, 0.f, 0.f, 0.f}, oA1 = oA0, oA2 = oA0, oA3 = oA0;
  f32x4 oB0 = oA0, oB1 = oA0, oB2 = oA0, oB3 = oA0;
#pragma unroll
  for (int t = 0; t < 8; ++t) {
    const unsigned short* vp = vh + t * 2048;
    short8 v0 = *(const short8*)vp;
    short8 v1 = *(const short8*)(vp + 512);
    short8 v2 = *(const short8*)(vp + 1024);
    short8 v3 = *(const short8*)(vp + 1536);

    union { unsigned u[4]; short8 s8v; } ua, ub;
    ua.u[0] = pafA[t][0]; ua.u[1] = pafA[t][1];
    ua.u[2] = pafA[t][2]; ua.u[3] = pafA[t][3];
    ub.u[0] = pafB[t][0]; ub.u[1] = pafB[t][1];
    ub.u[2] = pafB[t][2]; ub.u[3] = pafB[t][3];
    const short8 pa = ua.s8v, pb = ub.s8v;
    oA0 = MFMA16(pa, v0, oA0);
    oA1 = MFMA16(pa, v1, oA1);
    oA2 = MFMA16(pa, v2, oA2);
    oA3 = MFMA16(pa, v3, oA3);
    oB0 = MFMA16(pb, v0, oB0);
    oB1 = MFMA16(pb, v1, oB1);
    oB2 = MFMA16(pb, v2, oB2);
    oB3 = MFMA16(pb, v3, oB3);

    f32x4 p0, p1;
    p0[0] = u2f(pafA[t][0] << 16) * invA;
    p0[1] = u2f(pafA[t][0] & 0xffff0000u) * invA;
    p0[2] = u2f(pafA[t][1] << 16) * invA;
    p0[3] = u2f(pafA[t][1] & 0xffff0000u) * invA;
    p1[0] = u2f(pafA[t][2] << 16) * invA;
    p1[1] = u2f(pafA[t][2] & 0xffff0000u) * invA;
    p1[2] = u2f(pafA[t][3] << 16) * invA;
    p1[3] = u2f(pafA[t][3] & 0xffff0000u) * invA;
    *(f32x4*)&prowA[t * 32] = p0;
    *(f32x4*)&prowA[t * 32 + 4] = p1;
    f32x4 q0, q1;
    q0[0] = u2f(pafB[t][0] << 16) * invB;
    q0[1] = u2f(pafB[t][0] & 0xffff0000u) * invB;
    q0[2] = u2f(pafB[t][1] << 16) * invB;
    q0[3] = u2f(pafB[t][1] & 0xffff0000u) * invB;
    q1[0] = u2f(pafB[t][2] << 16) * invB;
    q1[1] = u2f(pafB[t][2] & 0xffff0000u) * invB;
    q1[2] = u2f(pafB[t][3] << 16) * invB;
    q1[3] = u2f(pafB[t][3] & 0xffff0000u) * invB;
    *(f32x4*)&prowB[t * 32] = q0;
    *(f32x4*)&prowB[t * 32 + 4] = q1;
  }

  // partial PV -> LDS
#pragma unroll
  for (int g = 0; g < 4; ++g) {
    red[w][0][Qr * 4 + g][lq] = oA0[g];
    red[w][1][Qr * 4 + g][lq] = oA1[g];
    red[w][2][Qr * 4 + g][lq] = oA2[g];
    red[w][3][Qr * 4 + g][lq] = oA3[g];
    red[w][0][16 + Qr * 4 + g][lq] = oB0[g];
    red[w][1][16 + Qr * 4 + g][lq] = oB1[g];
    red[w][2][16 + Qr * 4 + g][lq] = oB2[g];
    red[w][3][16 + Qr * 4 + g][lq] = oB3[g];
  }
  __syncthreads();

  // ctx: thread -> q = tid>>3 (0..31), d = (tid&7)*8 + j
  {
    const int qrow = tid >> 3;
    const int d0 = (tid & 7) * 8;
    const float invq = 1.0f / (reds[0][qrow] + reds[1][qrow] +
                               reds[2][qrow] + reds[3][qrow]);
    u16x4 cv0, cv1;
#pragma unroll
    for (int j = 0; j < 8; ++j) {
      const int d = d0 + j;
      const int db = d >> 4, dd = d & 15;
      float sum = red[0][db][qrow][dd] + red[1][db][qrow][dd] +
                  red[2][db][qrow][dd] + red[3][db][qrow][dd];
      if (j < 4) cv0[j] = f2bf(sum * invq);
      else       cv1[j - 4] = f2bf(sum * invq);
    }
    unsigned short* cb =
        ctx + ((size_t)(b * 1024 + qA + qrow)) * 1024 + hd * 64 + d0;
    *(u16x4*)cb = cv0;
    *(u16x4*)(cb + 4) = cv1;
  }
}

// ---------------------------------------------------------------- launch
extern "C" void kernel_launch(void* const* d_in, const int* in_sizes, int n_in,
                              void* d_out, int out_size, void* d_ws, size_t ws_size,
                              hipStream_t stream) {
  const float* hs = (const float*)d_in[0];
  const float* Wq = (const float*)d_in[1];
  const float* bq = (const float*)d_in[2];
  const float* Wk = (const float*)d_in[3];
  const float* bk = (const float*)d_in[4];
  const float* Wv = (const float*)d_in[5];
  const float* bv = (const float*)d_in[6];
  const float* Wo = (const float*)d_in[7];
  const float* bo = (const float*)d_in[8];
  const float* de = (const float*)d_in[9];

  float* out = (float*)d_out;
  float* probs = out + (size_t)4 * 1024 * 1024;

  char* ws = (char*)d_ws;
  unsigned short* Xb  = (unsigned short*)(ws);                      // -> ctx later
  unsigned short* Wqb = (unsigned short*)(ws + ((size_t)8 << 20));
  unsigned short* Wkb = (unsigned short*)(ws + ((size_t)10 << 20));
  unsigned short* Wvb = (unsigned short*)(ws + ((size_t)12 << 20));
  unsigned short* Wob = (unsigned short*)(ws + ((size_t)14 << 20));
  unsigned short* Qb  = (unsigned short*)(ws + ((size_t)16 << 20));
  unsigned short* Kb  = (unsigned short*)(ws + ((size_t)24 << 20));
  unsigned short* Vt  = (unsigned short*)(ws + ((size_t)32 << 20));
  unsigned short* Db  = (unsigned short*)(ws + ((size_t)40 << 20));  // own slot
  unsigned short* Cx  = Xb;   // ctx (after QKV gemm; X dead)

  cvt_f32_bf16<<<dim3(1024), dim3(256), 0, stream>>>(hs, Xb, (4 * 1024 * 1024) / 4);
  cvt_w4d<<<dim3(1025), dim3(256), 0, stream>>>(Wq, Wk, Wv, Wo, de,
                                                Wqb, Wkb, Wvb, Wob, Db);

  gemm_qkv3<<<dim3(768), dim3(256), 0, stream>>>(Xb, Wqb, Wkb, Wvb, bq, bk, bv,
                                                 Qb, Kb, Vt);

  attn_kernel<<<dim3(2048), dim3(256), 0, stream>>>(Qb, Kb, Vt, Db, probs, Cx);

  gemm_nt_f32<<<dim3(32, 8), dim3(256), 0, stream>>>(Cx, Wob, bo, out);
}